// Round 11
// baseline (363.456 us; speedup 1.0000x reference)
//
#include <hip/hip_runtime.h>
#include <stdint.h>

#define XDIM 131
#define GSZ 513
#define TROWS 64
#define SC_OFF 32768           // 32 k-blocks * 1024 B, then 1 KB scratch

typedef __attribute__((ext_vector_type(8))) short bf16x8;
typedef __attribute__((ext_vector_type(4))) float f32x4;
typedef unsigned int uint32;

// one-instruction pack: 2 f32 -> 2 bf16 (RTNE), v_cvt_pk_bf16_f32
__device__ __forceinline__ uint32 pk2bf(float a, float b) {
  uint32 r;
  asm volatile("v_cvt_pk_bf16_f32 %0, %1, %2" : "=v"(r) : "v"(a), "v"(b));
  return r;
}
__device__ __forceinline__ unsigned short f2bf(float f) {
  return (unsigned short)pk2bf(f, f);
}
__device__ __forceinline__ float bf2f(unsigned short s) {
  return __uint_as_float(((uint32)s) << 16);
}
__device__ __forceinline__ int slot16(int r) { return (r * 16) ^ (((r >> 3) & 1) << 5); }

// ---------------- prep: P [3][32][513][513] f32 -> Pt [3][513][513][32] bf16
__global__ void prep_pt(const float* __restrict__ P, unsigned short* __restrict__ Pt) {
  int i = blockIdx.x * 256 + threadIdx.x;
  const int CELLS = 3 * GSZ * GSZ;
  if (i >= CELLS) return;
  int pl = i / (GSZ * GSZ);
  int yx = i - pl * (GSZ * GSZ);
  const float* src = P + (size_t)pl * 32 * GSZ * GSZ + yx;
  const size_t GG = (size_t)GSZ * GSZ;
  uint4* dst = (uint4*)(Pt + (size_t)i * 32);
#pragma unroll
  for (int w = 0; w < 4; ++w) {
    uint4 t;
    t.x = pk2bf(src[(w * 8 + 0) * GG], src[(w * 8 + 1) * GG]);
    t.y = pk2bf(src[(w * 8 + 2) * GG], src[(w * 8 + 3) * GG]);
    t.z = pk2bf(src[(w * 8 + 4) * GG], src[(w * 8 + 5) * GG]);
    t.w = pk2bf(src[(w * 8 + 6) * GG], src[(w * 8 + 7) * GG]);
    dst[w] = t;
  }
}

// ---------------- prep: W0/W1 -> bf16 MFMA B-frag order [kb][lg][n][8], W0 K-permuted
__global__ void prep_w(const float* __restrict__ W0, const float* __restrict__ W1,
                       unsigned short* __restrict__ W0g, unsigned short* __restrict__ W1g) {
  int i = blockIdx.x * 256 + threadIdx.x;  // 0..16383
  int sel = i >> 13;
  int t = i & 8191;
  int kb = t >> 10;
  int g  = (t >> 8) & 3;
  int n  = t & 255;
  float vv[8];
#pragma unroll
  for (int j = 0; j < 8; ++j) {
    int k = kb * 32 + g * 8 + j;
    float val;
    if (sel == 0) {
      int src = (k < 131) ? k : ((k >= 136 && k < 232) ? k - 5 : -1);
      val = (src >= 0) ? W0[src * 256 + n] : 0.f;
    } else {
      val = W1[k * 256 + n];
    }
    vv[j] = val;
  }
  uint4 o;
  o.x = pk2bf(vv[0], vv[1]);
  o.y = pk2bf(vv[2], vv[3]);
  o.z = pk2bf(vv[4], vv[5]);
  o.w = pk2bf(vv[6], vv[7]);
  unsigned short* dst = (sel == 0 ? W0g : W1g) + (size_t)t * 8;
  *(uint4*)dst = o;
}

// ---------------- gather kernel: triplane bilinear -> feats[N][96] bf16
__global__ __launch_bounds__(256) void k_gather(
    const float* __restrict__ x, const unsigned short* __restrict__ Pt,
    unsigned short* __restrict__ feats, int Npts)
{
  int idx = blockIdx.x * 256 + threadIdx.x;
  int p = min(idx >> 2, Npts - 1);
  int q = idx & 3;                      // 8 channels each
  const float* xr = x + (size_t)p * XDIM + 128;
  float cc0 = xr[0], cc1 = xr[1], cc2 = xr[2];

  const unsigned short* pp[12];
  float w[12];
#pragma unroll
  for (int pl = 0; pl < 3; ++pl) {
    float u = (pl == 2) ? cc1 : cc0;
    float v = (pl == 0) ? cc1 : cc2;
    float gx = fminf(fmaxf((u + 1.f) * 256.f, 0.f), 512.f);
    float gy = fminf(fmaxf((v + 1.f) * 256.f, 0.f), 512.f);
    float x0f = floorf(gx), y0f = floorf(gy);
    int x0 = (int)x0f, y0 = (int)y0f;
    int x1 = min(x0 + 1, GSZ - 1), y1 = min(y0 + 1, GSZ - 1);
    float wx = gx - x0f, wy = gy - y0f;
    w[pl * 4 + 0] = (1.f - wx) * (1.f - wy);
    w[pl * 4 + 1] = wx * (1.f - wy);
    w[pl * 4 + 2] = (1.f - wx) * wy;
    w[pl * 4 + 3] = wx * wy;
    const unsigned short* pb = Pt + (size_t)pl * GSZ * GSZ * 32 + q * 8;
    pp[pl * 4 + 0] = pb + (size_t)(y0 * GSZ + x0) * 32;
    pp[pl * 4 + 1] = pb + (size_t)(y0 * GSZ + x1) * 32;
    pp[pl * 4 + 2] = pb + (size_t)(y1 * GSZ + x0) * 32;
    pp[pl * 4 + 3] = pb + (size_t)(y1 * GSZ + x1) * 32;
  }
  bf16x8 v[12];
#pragma unroll
  for (int j = 0; j < 12; ++j) v[j] = *(const bf16x8*)pp[j];

#pragma unroll
  for (int pl = 0; pl < 3; ++pl) {
    float f[8];
#pragma unroll
    for (int j = 0; j < 8; ++j) {
      f[j] = w[pl * 4 + 0] * bf2f((unsigned short)v[pl * 4 + 0][j])
           + w[pl * 4 + 1] * bf2f((unsigned short)v[pl * 4 + 1][j])
           + w[pl * 4 + 2] * bf2f((unsigned short)v[pl * 4 + 2][j])
           + w[pl * 4 + 3] * bf2f((unsigned short)v[pl * 4 + 3][j]);
    }
    uint4 fv;
    fv.x = pk2bf(f[0], f[1]);
    fv.y = pk2bf(f[2], f[3]);
    fv.z = pk2bf(f[4], f[5]);
    fv.w = pk2bf(f[6], f[7]);
    *(uint4*)(feats + (size_t)p * 96 + pl * 32 + q * 8) = fv;
  }
}

// 64x64-per-wave GEMM over K=256: single live B-frag, setprio(1) around MFMA cluster.
__device__ __forceinline__ void gemm64(const unsigned char* __restrict__ lds_,
                                       const unsigned short* __restrict__ Wg,
                                       int cg, int lr, int lg, f32x4 (&acc)[4][4])
{
#pragma unroll
  for (int kb = 0; kb < 8; ++kb) {
    bf16x8 a[4];
    const unsigned char* ab = lds_ + (kb * 4 + lg) * 1024;
#pragma unroll
    for (int mf = 0; mf < 4; ++mf)
      a[mf] = *(const bf16x8*)(ab + slot16(mf * 16 + lr));
    const unsigned short* wb = Wg + ((size_t)(kb * 4 + lg) * 256 + cg * 64 + lr) * 8;
    __builtin_amdgcn_s_setprio(1);
#pragma unroll
    for (int nf = 0; nf < 4; ++nf) {
      bf16x8 b = *(const bf16x8*)(wb + nf * 128);
#pragma unroll
      for (int mf = 0; mf < 4; ++mf)
        acc[mf][nf] = __builtin_amdgcn_mfma_f32_16x16x32_bf16(a[mf], b, acc[mf][nf], 0, 0, 0);
    }
    __builtin_amdgcn_s_setprio(0);
  }
}

// MODE: 0 = split (feats precomputed), 1 = fused w/ Pt, 2 = fused w/ raw P
template<int MODE>
__global__ __launch_bounds__(256, 4) void sdf_mlp(
    const float* __restrict__ x, const float* __restrict__ P,
    const unsigned short* __restrict__ Pt, const unsigned short* __restrict__ feats,
    const unsigned short* __restrict__ W0g, const unsigned short* __restrict__ W1g,
    const float* __restrict__ b0, const float* __restrict__ b1,
    const float* __restrict__ W2, const float* __restrict__ b2v,
    float* __restrict__ out, int Npts)
{
  __shared__ __align__(16) unsigned char lds[SC_OFF + 1024];

  const int tid = threadIdx.x;
  const int p0 = blockIdx.x * TROWS;
  const int lane = tid & 63, cg = tid >> 6;       // 4 waves, wave = 64-col group
  const int lr = lane & 15, lg = lane >> 4;

  // ---- stage x cols 0..127 -> blocks 0..15
#pragma unroll
  for (int i = 0; i < 4; ++i) {
    int t = i * 256 + tid;
    int cb = t & 15, r = t >> 4;
    int p = min(p0 + r, Npts - 1);
    const float* src = x + (size_t)p * XDIM + cb * 8;
    uint4 v;
    v.x = pk2bf(src[0], src[1]);
    v.y = pk2bf(src[2], src[3]);
    v.z = pk2bf(src[4], src[5]);
    v.w = pk2bf(src[6], src[7]);
    *(uint4*)(lds + cb * 1024 + slot16(r)) = v;
  }
  // coords block 16 (cols 128..130 + zero pad); zero blocks 29..31 (192 uint4)
  if (tid < 64) {
    int p = min(p0 + tid, Npts - 1);
    const float* xr = x + (size_t)p * XDIM + 128;
    uint4 v;
    v.x = pk2bf(xr[0], xr[1]);
    v.y = pk2bf(xr[2], 0.f);
    v.z = 0u; v.w = 0u;
    *(uint4*)(lds + 16 * 1024 + slot16(tid)) = v;
  } else {
    uint4 z = {0u, 0u, 0u, 0u};
    ((uint4*)(lds + 29 * 1024))[tid - 64] = z;    // 192 uint4 = blocks 29..31
  }

  if (MODE == 0) {
    // ---- feats staging: pure bf16 copy, blocks 17..28 (768 uint4 tasks)
#pragma unroll
    for (int i = 0; i < 3; ++i) {
      int t = i * 256 + tid;
      int r = t & 63, j = t >> 6;                 // j = 0..11
      int p = min(p0 + r, Npts - 1);
      uint4 fv = *(const uint4*)(feats + (size_t)p * 96 + j * 8);
      *(uint4*)(lds + (17 + j) * 1024 + slot16(r)) = fv;
    }
  } else {
    // ---- fused triplane gather -> blocks 17..28; 4 thr/pt
    int p_l = tid >> 2, q = tid & 3;
    int p = min(p0 + p_l, Npts - 1);
    const float* xr = x + (size_t)p * XDIM + 128;
    float cc0 = xr[0], cc1 = xr[1], cc2 = xr[2];
#pragma unroll
    for (int pl = 0; pl < 3; ++pl) {
      float u = (pl == 2) ? cc1 : cc0;
      float v = (pl == 0) ? cc1 : cc2;
      float gx = fminf(fmaxf((u + 1.f) * 256.f, 0.f), 512.f);
      float gy = fminf(fmaxf((v + 1.f) * 256.f, 0.f), 512.f);
      float x0f = floorf(gx), y0f = floorf(gy);
      int x0 = (int)x0f, y0 = (int)y0f;
      int x1 = min(x0 + 1, GSZ - 1), y1 = min(y0 + 1, GSZ - 1);
      float wx = gx - x0f, wy = gy - y0f;
      float w00 = (1.f - wx) * (1.f - wy), w01 = wx * (1.f - wy);
      float w10 = (1.f - wx) * wy,        w11 = wx * wy;
      float f[8];
      if (MODE == 1) {
        const unsigned short* pb = Pt + (size_t)pl * GSZ * GSZ * 32 + q * 8;
        bf16x8 v00 = *(const bf16x8*)(pb + (size_t)(y0 * GSZ + x0) * 32);
        bf16x8 v01 = *(const bf16x8*)(pb + (size_t)(y0 * GSZ + x1) * 32);
        bf16x8 v10 = *(const bf16x8*)(pb + (size_t)(y1 * GSZ + x0) * 32);
        bf16x8 v11 = *(const bf16x8*)(pb + (size_t)(y1 * GSZ + x1) * 32);
#pragma unroll
        for (int j = 0; j < 8; ++j) {
          f[j] = w00 * bf2f((unsigned short)v00[j]) + w01 * bf2f((unsigned short)v01[j])
               + w10 * bf2f((unsigned short)v10[j]) + w11 * bf2f((unsigned short)v11[j]);
        }
      } else {
#pragma unroll
        for (int j = 0; j < 8; ++j) {
          const float* pc = P + (size_t)(pl * 32 + q * 8 + j) * GSZ * GSZ;
          f[j] = w00 * pc[y0 * GSZ + x0] + w01 * pc[y0 * GSZ + x1]
               + w10 * pc[y1 * GSZ + x0] + w11 * pc[y1 * GSZ + x1];
        }
      }
      uint4 fv;
      fv.x = pk2bf(f[0], f[1]);
      fv.y = pk2bf(f[2], f[3]);
      fv.z = pk2bf(f[4], f[5]);
      fv.w = pk2bf(f[6], f[7]);
      *(uint4*)(lds + (17 + pl * 4 + q) * 1024 + slot16(p_l)) = fv;
    }
  }
  __syncthreads();

  // ---- layer 0 (K=256 padded)
  {
    f32x4 acc[4][4];
#pragma unroll
    for (int mf = 0; mf < 4; ++mf)
#pragma unroll
      for (int nf = 0; nf < 4; ++nf) acc[mf][nf] = (f32x4){0.f, 0.f, 0.f, 0.f};
    gemm64(lds, W0g, cg, lr, lg, acc);
    __syncthreads();               // all A-reads of act done before overwrite with h
#pragma unroll
    for (int nf = 0; nf < 4; ++nf) {
      int col = cg * 64 + nf * 16 + lr;
      float bs = b0[col];
      unsigned char* base = lds + (col >> 3) * 1024 + (col & 7) * 2;
#pragma unroll
      for (int mf = 0; mf < 4; ++mf)
#pragma unroll
        for (int reg = 0; reg < 4; ++reg) {
          int row = mf * 16 + lg * 4 + reg;
          *(unsigned short*)(base + slot16(row)) = f2bf(fmaxf(acc[mf][nf][reg] + bs, 0.f));
        }
    }
  }
  __syncthreads();

  // ---- layer 1 + fused W2 dot from accumulators (no h1 writeback)
  {
    f32x4 acc[4][4];
#pragma unroll
    for (int mf = 0; mf < 4; ++mf)
#pragma unroll
      for (int nf = 0; nf < 4; ++nf) acc[mf][nf] = (f32x4){0.f, 0.f, 0.f, 0.f};
    gemm64(lds, W1g, cg, lr, lg, acc);

    float part[4][4];
#pragma unroll
    for (int mf = 0; mf < 4; ++mf)
#pragma unroll
      for (int reg = 0; reg < 4; ++reg) part[mf][reg] = 0.f;
#pragma unroll
    for (int nf = 0; nf < 4; ++nf) {
      int col = cg * 64 + nf * 16 + lr;
      float bs = b1[col];
      float w2v = W2[col];
#pragma unroll
      for (int mf = 0; mf < 4; ++mf)
#pragma unroll
        for (int reg = 0; reg < 4; ++reg)
          part[mf][reg] += fmaxf(acc[mf][nf][reg] + bs, 0.f) * w2v;
    }
#pragma unroll
    for (int mf = 0; mf < 4; ++mf)
#pragma unroll
      for (int reg = 0; reg < 4; ++reg) {
        float v = part[mf][reg];
        v += __shfl_xor(v, 1);
        v += __shfl_xor(v, 2);
        v += __shfl_xor(v, 4);
        v += __shfl_xor(v, 8);
        part[mf][reg] = v;
      }
    if (lr == 0) {
      float* sc = (float*)(lds + SC_OFF) + cg * 64;
#pragma unroll
      for (int mf = 0; mf < 4; ++mf) {
        float4 pv;
        pv.x = part[mf][0]; pv.y = part[mf][1]; pv.z = part[mf][2]; pv.w = part[mf][3];
        *(float4*)(sc + mf * 16 + lg * 4) = pv;   // row = mf*16+lg*4+reg
      }
    }
  }
  __syncthreads();
  if (tid < 64) {
    const float* sc = (const float*)(lds + SC_OFF);
    float s = sc[tid] + sc[64 + tid] + sc[128 + tid] + sc[192 + tid] + b2v[0];
    int p = p0 + tid;
    if (p < Npts) out[p] = s;
  }
}

extern "C" void kernel_launch(void* const* d_in, const int* in_sizes, int n_in,
                              void* d_out, int out_size, void* d_ws, size_t ws_size,
                              hipStream_t stream)
{
  const float* x  = (const float*)d_in[0];
  const float* P  = (const float*)d_in[1];
  const float* W0 = (const float*)d_in[2];
  const float* b0 = (const float*)d_in[3];
  const float* W1 = (const float*)d_in[4];
  const float* b1 = (const float*)d_in[5];
  const float* W2 = (const float*)d_in[6];
  const float* b2 = (const float*)d_in[7];
  float* out = (float*)d_out;
  int Npts = in_sizes[0] / XDIM;

  const size_t PT_BYTES = (size_t)3 * GSZ * GSZ * 32 * 2;   // ~50.5 MB
  const size_t WG_BYTES = (size_t)8192 * 8 * 2;             // 128 KB each
  const size_t FT_BYTES = (size_t)Npts * 96 * 2;            // ~96 MB
  char* ws = (char*)d_ws;

  int mode;
  unsigned short *Ptb = nullptr, *W0g, *W1g, *ft = nullptr;
  if (ws_size >= PT_BYTES + 2 * WG_BYTES + FT_BYTES) {
    mode = 0;
    Ptb = (unsigned short*)ws;
    W0g = (unsigned short*)(ws + PT_BYTES);
    W1g = (unsigned short*)(ws + PT_BYTES + WG_BYTES);
    ft  = (unsigned short*)(ws + PT_BYTES + 2 * WG_BYTES);
  } else if (ws_size >= PT_BYTES + 2 * WG_BYTES) {
    mode = 1;
    Ptb = (unsigned short*)ws;
    W0g = (unsigned short*)(ws + PT_BYTES);
    W1g = (unsigned short*)(ws + PT_BYTES + WG_BYTES);
  } else {
    mode = 2;
    W0g = (unsigned short*)ws;
    W1g = (unsigned short*)(ws + WG_BYTES);
  }

  prep_w<<<64, 256, 0, stream>>>(W0, W1, W0g, W1g);
  if (mode != 2) prep_pt<<<(3 * GSZ * GSZ + 255) / 256, 256, 0, stream>>>(P, Ptb);
  if (mode == 0) k_gather<<<(Npts * 4 + 255) / 256, 256, 0, stream>>>(x, Ptb, ft, Npts);

  int nblk = (Npts + TROWS - 1) / TROWS;
  if (mode == 0)
    sdf_mlp<0><<<nblk, 256, 0, stream>>>(x, P, Ptb, ft, W0g, W1g, b0, b1, W2, b2, out, Npts);
  else if (mode == 1)
    sdf_mlp<1><<<nblk, 256, 0, stream>>>(x, P, Ptb, ft, W0g, W1g, b0, b1, W2, b2, out, Npts);
  else
    sdf_mlp<2><<<nblk, 256, 0, stream>>>(x, P, Ptb, ft, W0g, W1g, b0, b1, W2, b2, out, Npts);
}